// Round 2
// baseline (228.967 us; speedup 1.0000x reference)
//
#include <hip/hip_runtime.h>
#include <hip/hip_bf16.h>

#define N_ROWS 131072
#define K_MIX  256
#define D_DIM  128
#define LDSB_STRIDE 136            // shorts per B row: 128 + 8 pad (rows 272 B, 16B aligned)
#define B_CHUNKS (K_MIX * LDSB_STRIDE / 8)   // 4352 bf16x8 chunks = 69632 B

typedef float  f32x4  __attribute__((ext_vector_type(4)));
typedef short  bf16x8 __attribute__((ext_vector_type(8)));

__device__ inline bf16x8 pack8(float4 a, float4 b) {
    union { bf16x8 v; __hip_bfloat162 h[4]; } u;
    u.h[0] = __float22bfloat162_rn(make_float2(a.x, a.y));
    u.h[1] = __float22bfloat162_rn(make_float2(a.z, a.w));
    u.h[2] = __float22bfloat162_rn(make_float2(b.x, b.y));
    u.h[3] = __float22bfloat162_rn(make_float2(b.z, b.w));
    return u.v;
}

// ---------------- prep: ws <- padded bf16(prec*mu), fp32 musq ----------------
__global__ void prep_kernel(const float* __restrict__ mu,
                            const float* __restrict__ prec,
                            unsigned short* __restrict__ Bp,
                            float* __restrict__ musq)
{
    int idx = blockIdx.x * 256 + threadIdx.x;   // 0..8191 float4s of mu
    int row = idx >> 5;                          // mixture component k
    int c4  = idx & 31;                          // float4 within row
    float4 mv = ((const float4*)mu)[idx];
    float4 pv = ((const float4*)prec)[c4];
    float px = mv.x * pv.x, py = mv.y * pv.y, pz = mv.z * pv.z, pw = mv.w * pv.w;
    union { ushort4 u4; __hip_bfloat162 h[2]; } h;
    h.h[0] = __float22bfloat162_rn(make_float2(px, py));
    h.h[1] = __float22bfloat162_rn(make_float2(pz, pw));
    *(ushort4*)&Bp[row * LDSB_STRIDE + c4 * 4] = h.u4;
    if (c4 == 31) {     // zero the 8-short pad (16 B, aligned: row*272+256)
        bf16x8 z = (bf16x8)0;
        *(bf16x8*)&Bp[row * LDSB_STRIDE + 128] = z;
    }
    float ps = px * mv.x + py * mv.y + pz * mv.z + pw * mv.w;
    ps += __shfl_xor(ps, 1);  ps += __shfl_xor(ps, 2);
    ps += __shfl_xor(ps, 4);  ps += __shfl_xor(ps, 8);
    ps += __shfl_xor(ps, 16);
    if ((threadIdx.x & 31) == 0) musq[row] = ps;
}

// ---------------- main ----------------
__global__ __launch_bounds__(256, 2)
void mixture_main(const float* __restrict__ x,
                  const unsigned short* __restrict__ Bp,
                  const float* __restrict__ musqg,
                  const float* __restrict__ prec,
                  float* __restrict__ out)
{
    __shared__ __align__(16) unsigned short sB[K_MIX * LDSB_STRIDE];
    __shared__ float sMusq[K_MIX];
    __shared__ float sPrec[D_DIM];
    __shared__ float sRed[4];

    const int tid  = threadIdx.x;
    const int lane = tid & 63;
    const int wave = tid >> 6;
    const int low4 = lane & 15;
    const int q    = lane >> 4;

    // ---- stage B image (already padded+converted), musq, prec ----
    {
        const bf16x8* src = (const bf16x8*)Bp;
        bf16x8* dst = (bf16x8*)sB;
        #pragma unroll
        for (int i = 0; i < B_CHUNKS / 256; ++i)   // 17 iterations
            dst[i * 256 + tid] = src[i * 256 + tid];
        sMusq[tid] = musqg[tid];
        if (tid < D_DIM) sPrec[tid] = prec[tid];
    }
    __syncthreads();

    const float4* x4 = (const float4*)x;
    float lacc = 0.f;    // accumulates 0.5*xs - lse

    #pragma unroll
    for (int rg = 0; rg < 2; ++rg) {
        const int rb = blockIdx.x * 256 + rg * 128 + wave * 32;
        const int r0 = rb + low4;
        const int r1 = r0 + 16;

        // ---- hoist ALL x loads for this row-group (16 float4, independent) ----
        float4 xv[4][4];
        #pragma unroll
        for (int k = 0; k < 4; ++k) {
            const int d4 = k * 8 + q * 2;
            xv[k][0] = x4[r0 * 32 + d4];
            xv[k][1] = x4[r0 * 32 + d4 + 1];
            xv[k][2] = x4[r1 * 32 + d4];
            xv[k][3] = x4[r1 * 32 + d4 + 1];
        }

        f32x4 acc[2][16];
        #pragma unroll
        for (int m = 0; m < 2; ++m)
            #pragma unroll
            for (int c = 0; c < 16; ++c)
                acc[m][c] = (f32x4){0.f, 0.f, 0.f, 0.f};

        float xs0 = 0.f, xs1 = 0.f, xs2 = 0.f, xs3 = 0.f;

        #pragma unroll
        for (int k = 0; k < 4; ++k) {
            const int d4 = k * 8 + q * 2;
            float4 pa = *(const float4*)&sPrec[d4 * 4];       // broadcast LDS read
            float4 pb = *(const float4*)&sPrec[d4 * 4 + 4];

            xs0 += pa.x*xv[k][0].x*xv[k][0].x + pa.y*xv[k][0].y*xv[k][0].y
                 + pa.z*xv[k][0].z*xv[k][0].z + pa.w*xv[k][0].w*xv[k][0].w;
            xs1 += pb.x*xv[k][1].x*xv[k][1].x + pb.y*xv[k][1].y*xv[k][1].y
                 + pb.z*xv[k][1].z*xv[k][1].z + pb.w*xv[k][1].w*xv[k][1].w;
            xs2 += pa.x*xv[k][2].x*xv[k][2].x + pa.y*xv[k][2].y*xv[k][2].y
                 + pa.z*xv[k][2].z*xv[k][2].z + pa.w*xv[k][2].w*xv[k][2].w;
            xs3 += pb.x*xv[k][3].x*xv[k][3].x + pb.y*xv[k][3].y*xv[k][3].y
                 + pb.z*xv[k][3].z*xv[k][3].z + pb.w*xv[k][3].w*xv[k][3].w;

            bf16x8 a0 = pack8(xv[k][0], xv[k][1]);
            bf16x8 a1 = pack8(xv[k][2], xv[k][3]);

            #pragma unroll
            for (int c = 0; c < 16; ++c) {
                const unsigned short* bp =
                    &sB[(c * 16 + low4) * LDSB_STRIDE + k * 32 + q * 8];
                bf16x8 b = *(const bf16x8*)bp;   // ds_read_b128, 16B aligned
                acc[0][c] = __builtin_amdgcn_mfma_f32_16x16x32_bf16(a0, b, acc[0][c], 0, 0, 0);
                acc[1][c] = __builtin_amdgcn_mfma_f32_16x16x32_bf16(a1, b, acc[1][c], 0, 0, 0);
            }
        }
        float xs = (xs0 + xs1) + (xs2 + xs3);

        // ---- epilogue: per-row logsumexp of (cross - 0.5*musq) ----
        float musq_l[16];
        #pragma unroll
        for (int c = 0; c < 16; ++c) musq_l[c] = 0.5f * sMusq[c * 16 + low4];

        float lsum = 0.f;
        #pragma unroll
        for (int m = 0; m < 2; ++m) {
            #pragma unroll
            for (int i = 0; i < 4; ++i) {
                float vmax = -1e30f;
                #pragma unroll
                for (int c = 0; c < 16; ++c) {
                    float v = acc[m][c][i] - musq_l[c];
                    vmax = fmaxf(vmax, v);
                }
                vmax = fmaxf(vmax, __shfl_xor(vmax, 1));
                vmax = fmaxf(vmax, __shfl_xor(vmax, 2));
                vmax = fmaxf(vmax, __shfl_xor(vmax, 4));
                vmax = fmaxf(vmax, __shfl_xor(vmax, 8));
                float s = 0.f;
                #pragma unroll
                for (int c = 0; c < 16; ++c) {
                    float v = acc[m][c][i] - musq_l[c];
                    s += __expf(v - vmax);
                }
                s += __shfl_xor(s, 1); s += __shfl_xor(s, 2);
                s += __shfl_xor(s, 4); s += __shfl_xor(s, 8);
                if (low4 == 0) lsum += vmax + __logf(s);
            }
        }
        lacc += 0.5f * xs - lsum;
    }

    // ---- block reduction, one atomic ----
    lacc += __shfl_xor(lacc, 32); lacc += __shfl_xor(lacc, 16);
    lacc += __shfl_xor(lacc, 8);  lacc += __shfl_xor(lacc, 4);
    lacc += __shfl_xor(lacc, 2);  lacc += __shfl_xor(lacc, 1);
    if (lane == 0) sRed[wave] = lacc;
    __syncthreads();
    if (tid == 0) atomicAdd(out, sRed[0] + sRed[1] + sRed[2] + sRed[3]);
}

extern "C" void kernel_launch(void* const* d_in, const int* in_sizes, int n_in,
                              void* d_out, int out_size, void* d_ws, size_t ws_size,
                              hipStream_t stream) {
    const float* x    = (const float*)d_in[0];
    const float* mu   = (const float*)d_in[1];
    const float* prec = (const float*)d_in[2];
    float* out = (float*)d_out;

    unsigned short* Bp = (unsigned short*)d_ws;                      // 69632 B
    float* musq = (float*)((char*)d_ws + K_MIX * LDSB_STRIDE * 2);   // +1024 B

    hipMemsetAsync(d_out, 0, sizeof(float), stream);
    prep_kernel<<<32, 256, 0, stream>>>(mu, prec, Bp, musq);
    mixture_main<<<N_ROWS / 256, 256, 0, stream>>>(x, Bp, musq, prec, out);
}